// Round 1
// baseline (70.366 us; speedup 1.0000x reference)
//
#include <hip/hip_runtime.h>

// PackedStdScaler: grouped (sample_id, variate_id) masked mean/std over (B,S,D)
// B=4, S=2048, D=128; sample_id,variate_id in [0,8) -> 64 groups/batch.
// One block per (b, group): computes group stats and writes loc/scale for all
// rows in that group. Every row belongs to exactly one group -> full coverage.

#define BB 4
#define SS 2048
#define DD 128
#define NG 64

__global__ __launch_bounds__(256) void pss_kernel(
    const float* __restrict__ target,
    const unsigned* __restrict__ mask_raw,   // raw words of observed_mask buffer
    const int* __restrict__ sample_id,
    const int* __restrict__ variate_id,
    float* __restrict__ out)                 // [0,B*S): loc, [B*S,2*B*S): scale
{
    const int b    = blockIdx.y;
    const int g    = blockIdx.x;
    const int tid  = threadIdx.x;
    const int lane = tid & 63;
    const int wave = tid >> 6;

    __shared__ unsigned short rows[SS];
    __shared__ int nrows;
    __shared__ int mflag;
    __shared__ double red[4][3];
    __shared__ float bcast[2];

    if (tid == 0) { nrows = 0; mflag = 0; }
    __syncthreads();

    // --- mask dtype detection: byte-bool buffer => some of first 64 words > 1
    {
        unsigned w = mask_raw[tid & 63];
        if (w > 1u) atomicOr(&mflag, 1);
    }

    // --- gather rows belonging to group g of batch b
    for (int s = tid; s < SS; s += 256) {
        int key = sample_id[b * SS + s] * 8 + variate_id[b * SS + s];
        if (key == g) {
            int idx = atomicAdd(&nrows, 1);
            rows[idx] = (unsigned short)s;
        }
    }
    __syncthreads();
    const bool bytemask = (mflag != 0);
    const int M = nrows;

    // --- accumulate cnt / sum / sumsq over group's observed entries
    float  c  = 0.f;
    double s1 = 0.0, s2 = 0.0;
    for (int i = wave; i < M; i += 4) {
        const int s = rows[i];
        const size_t rowoff = ((size_t)(b * SS + s)) * DD;
        float2 tv = ((const float2*)(target + rowoff))[lane];
        int m0, m1;
        if (bytemask) {
            const unsigned char* mb = ((const unsigned char*)mask_raw) + rowoff;
            uchar2 mv = ((const uchar2*)mb)[lane];
            m0 = mv.x; m1 = mv.y;
        } else {
            int2 mv = ((const int2*)(((const int*)mask_raw) + rowoff))[lane];
            m0 = mv.x; m1 = mv.y;
        }
        if (m0) { c += 1.f; s1 += (double)tv.x; s2 += (double)tv.x * (double)tv.x; }
        if (m1) { c += 1.f; s1 += (double)tv.y; s2 += (double)tv.y * (double)tv.y; }
    }

    // --- wave reduce (64 lanes), then cross-wave via LDS
    for (int off = 32; off > 0; off >>= 1) {
        c  += __shfl_down(c,  off, 64);
        s1 += __shfl_down(s1, off, 64);
        s2 += __shfl_down(s2, off, 64);
    }
    if (lane == 0) { red[wave][0] = (double)c; red[wave][1] = s1; red[wave][2] = s2; }
    __syncthreads();

    if (tid == 0) {
        double cnt = 0, gs = 0, gss = 0;
        for (int w = 0; w < 4; w++) { cnt += red[w][0]; gs += red[w][1]; gss += red[w][2]; }
        // safe_div semantics: den==0 -> divide by 1
        double loc = gs / (cnt == 0.0 ? 1.0 : cnt);
        double varnum = gss - 2.0 * loc * gs + loc * loc * cnt;  // == sum((t-loc)^2 * obs)
        double den = cnt - 1.0;                                   // CORRECTION = 1
        double var = varnum / (den == 0.0 ? 1.0 : den);
        if (var < 0.0) var = 0.0;                                 // guard fp cancellation
        float locf   = (float)loc;
        float scalef = (float)sqrt(var + 1e-5);                   // MINIMUM_SCALE
        if (g < 8) { locf = 0.f; scalef = 1.f; }                  // sample_id==0 padding
        bcast[0] = locf; bcast[1] = scalef;
    }
    __syncthreads();

    const float locf = bcast[0], scalef = bcast[1];
    for (int i = tid; i < M; i += 256) {
        const int s = rows[i];
        out[b * SS + s]            = locf;
        out[BB * SS + b * SS + s]  = scalef;
    }
}

extern "C" void kernel_launch(void* const* d_in, const int* in_sizes, int n_in,
                              void* d_out, int out_size, void* d_ws, size_t ws_size,
                              hipStream_t stream) {
    const float*    target = (const float*)d_in[0];
    const unsigned* mask   = (const unsigned*)d_in[1];
    const int*      sid    = (const int*)d_in[2];
    const int*      vid    = (const int*)d_in[3];
    float*          out    = (float*)d_out;

    dim3 grid(NG, BB);
    hipLaunchKernelGGL(pss_kernel, grid, dim3(256), 0, stream,
                       target, mask, sid, vid, out);
}

// Round 2
// 66.246 us; speedup vs baseline: 1.0622x; 1.0622x over previous
//
#include <hip/hip_runtime.h>

// PackedStdScaler: grouped (sample_id, variate_id) masked mean/std over (B,S,D)
// B=4, S=2048, D=128; ids in [0,8) -> 64 groups/batch.
// One block per (b, group): block gathers its group's row list (ballot
// compaction), computes cnt/sum/sumsq over observed entries, then writes
// loc/scale for exactly those rows. Rows partition across groups -> full
// coverage of d_out.

#define BB 4
#define SS 2048
#define DD 128
#define NG 64
#define NT 512          // 8 waves/block for latency hiding
#define NW (NT / 64)

__global__ __launch_bounds__(NT) void pss_kernel(
    const float* __restrict__ target,
    const unsigned* __restrict__ mask_raw,   // raw words of observed_mask buffer
    const int* __restrict__ sample_id,
    const int* __restrict__ variate_id,
    float* __restrict__ out)                 // [0,B*S): loc, [B*S,2*B*S): scale
{
    const int b    = blockIdx.y;
    const int g    = blockIdx.x;
    const int tid  = threadIdx.x;
    const int lane = tid & 63;
    const int wave = tid >> 6;

    __shared__ unsigned short rows[SS];
    __shared__ int nrows;
    __shared__ int mflag;
    __shared__ double red[NW][3];
    __shared__ float bcast[2];

    if (tid == 0) { nrows = 0; mflag = 0; }
    __syncthreads();

    // --- mask dtype detection: byte-bool buffer => some of first 64 words > 1
    if (mask_raw[tid & 63] > 1u) atomicOr(&mflag, 1);

    // --- gather rows of group g (batch b): int4 id loads, ballot compaction.
    // NT*4 == SS: one iteration covers all ids.
    {
        const int4 sv = ((const int4*)(sample_id + b * SS))[tid];
        const int4 vv = ((const int4*)(variate_id + b * SS))[tid];
        int keys[4] = { sv.x * 8 + vv.x, sv.y * 8 + vv.y,
                        sv.z * 8 + vv.z, sv.w * 8 + vv.w };
        #pragma unroll
        for (int j = 0; j < 4; j++) {
            const bool hit = (keys[j] == g);
            const unsigned long long bal = __ballot(hit);
            if (bal) {
                int base;
                if (lane == 0) base = atomicAdd(&nrows, __popcll(bal));
                base = __shfl(base, 0, 64);
                if (hit) {
                    const int pre = __popcll(bal & ((1ull << lane) - 1ull));
                    rows[base + pre] = (unsigned short)(4 * tid + j);
                }
            }
        }
    }
    __syncthreads();
    const bool bytemask = (mflag != 0);
    const int M = nrows;

    // --- accumulate cnt / sum / sumsq over group's observed entries.
    // One wave per row: 64 lanes x float2 = full 128-wide row.
    float  c  = 0.f;
    double s1 = 0.0, s2 = 0.0;
    for (int i = wave; i < M; i += NW) {
        const int s = rows[i];
        const size_t rowoff = ((size_t)(b * SS + s)) * DD;
        const float2 tv = ((const float2*)(target + rowoff))[lane];
        int m0, m1;
        if (bytemask) {
            const uchar2 mv =
                ((const uchar2*)(((const unsigned char*)mask_raw) + rowoff))[lane];
            m0 = mv.x; m1 = mv.y;
        } else {
            const int2 mv =
                ((const int2*)(((const int*)mask_raw) + rowoff))[lane];
            m0 = mv.x; m1 = mv.y;
        }
        if (m0) { c += 1.f; s1 += (double)tv.x; s2 += (double)tv.x * (double)tv.x; }
        if (m1) { c += 1.f; s1 += (double)tv.y; s2 += (double)tv.y * (double)tv.y; }
    }

    // --- wave reduce (64 lanes), then cross-wave via LDS
    for (int off = 32; off > 0; off >>= 1) {
        c  += __shfl_down(c,  off, 64);
        s1 += __shfl_down(s1, off, 64);
        s2 += __shfl_down(s2, off, 64);
    }
    if (lane == 0) { red[wave][0] = (double)c; red[wave][1] = s1; red[wave][2] = s2; }
    __syncthreads();

    if (tid == 0) {
        double cnt = 0, gs = 0, gss = 0;
        for (int w = 0; w < NW; w++) {
            cnt += red[w][0]; gs += red[w][1]; gss += red[w][2];
        }
        // safe_div semantics: den==0 -> divide by 1
        const double loc = gs / (cnt == 0.0 ? 1.0 : cnt);
        double varnum = gss - 2.0 * loc * gs + loc * loc * cnt; // == sum((t-loc)^2*obs)
        if (varnum < 0.0) varnum = 0.0;                          // fp cancellation guard
        const double den = cnt - 1.0;                            // CORRECTION = 1
        const double var = varnum / (den == 0.0 ? 1.0 : den);
        float locf   = (float)loc;
        float scalef = (float)sqrt((var < 0.0 ? 0.0 : var) + 1e-5); // MINIMUM_SCALE
        if (g < 8) { locf = 0.f; scalef = 1.f; }                 // sample_id==0 padding
        bcast[0] = locf; bcast[1] = scalef;
    }
    __syncthreads();

    const float locf = bcast[0], scalef = bcast[1];
    for (int i = tid; i < M; i += NT) {
        const int s = rows[i];
        out[b * SS + s]           = locf;
        out[BB * SS + b * SS + s] = scalef;
    }
}

extern "C" void kernel_launch(void* const* d_in, const int* in_sizes, int n_in,
                              void* d_out, int out_size, void* d_ws, size_t ws_size,
                              hipStream_t stream) {
    const float*    target = (const float*)d_in[0];
    const unsigned* mask   = (const unsigned*)d_in[1];
    const int*      sid    = (const int*)d_in[2];
    const int*      vid    = (const int*)d_in[3];
    float*          out    = (float*)d_out;

    dim3 grid(NG, BB);
    hipLaunchKernelGGL(pss_kernel, grid, dim3(NT), 0, stream,
                       target, mask, sid, vid, out);
}